// Round 8
// baseline (561.539 us; speedup 1.0000x reference)
//
#include <hip/hip_runtime.h>
#include <stdint.h>

typedef __attribute__((ext_vector_type(8))) short s16x8;    // bf16 MFMA A/B frag (4 VGPRs)
typedef __attribute__((ext_vector_type(4))) float f32x4;    // MFMA C/D frag
typedef __attribute__((ext_vector_type(4))) unsigned short us4;

// ---- bf16 round-to-nearest-even (inputs are finite normals) ----
__device__ inline unsigned short bf_rne(float f) {
    union { float f; uint32_t u; } v; v.f = f;
    uint32_t u = v.u;
    u += 0x7FFFu + ((u >> 16) & 1u);
    return (unsigned short)(u >> 16);
}

// async global->LDS, 16B per lane; LDS dst is wave-uniform base + lane*16
#define GLD_LDS16(gp, lp)                                                     \
    __builtin_amdgcn_global_load_lds(                                         \
        (const __attribute__((address_space(1))) void*)(gp),                  \
        (__attribute__((address_space(3))) void*)(lp), 16, 0, 0)

#define LGKM(n) asm volatile("s_waitcnt lgkmcnt(" #n ")" ::: "memory")
#define VMC(n)  asm volatile("s_waitcnt vmcnt(" #n ")" ::: "memory")
#define SFENCE() __builtin_amdgcn_sched_barrier(0)

// ---------------- Fused prologue ----------------
// blocks [0,512):    prep — adapted = W + B@A -> bf16, scale = mag/rownorm, 8 rows/blk
// blocks [512,8704): cvt  — x fp32 -> bf16, unit-stride float4 -> us4
__global__ __launch_bounds__(256) void prologue_kernel(
    const float4* __restrict__ x4, us4* __restrict__ xbf4,
    const float4* __restrict__ W4,
    const float4* __restrict__ A4,   // [16][1024] float4
    const float* __restrict__ B,     // [4096][16]
    const float* __restrict__ mag,   // [4096]
    unsigned short* __restrict__ wbf,
    float* __restrict__ scale) {
    const int tid = threadIdx.x;
    if (blockIdx.x < 512) {
        const int m0 = blockIdx.x * 8;
        __shared__ float Bs[8][16];
        __shared__ float red[32];
        if (tid < 128) Bs[tid >> 4][tid & 15] = B[m0 * 16 + tid];
        __syncthreads();
        float ss[8] = {};
        for (int c = tid; c < 1024; c += 256) {
            float4 a[16];
#pragma unroll
            for (int r = 0; r < 16; ++r) a[r] = A4[r * 1024 + c];
#pragma unroll
            for (int i = 0; i < 8; ++i) {
                float4 w = W4[(size_t)(m0 + i) * 1024 + c];
#pragma unroll
                for (int r = 0; r < 16; ++r) {
                    const float br = Bs[i][r];
                    w.x += br * a[r].x; w.y += br * a[r].y;
                    w.z += br * a[r].z; w.w += br * a[r].w;
                }
                ss[i] += w.x * w.x + w.y * w.y + w.z * w.z + w.w * w.w;
                us4 o; o[0] = bf_rne(w.x); o[1] = bf_rne(w.y);
                o[2] = bf_rne(w.z); o[3] = bf_rne(w.w);
                *(us4*)&wbf[(size_t)(m0 + i) * 4096 + c * 4] = o;
            }
        }
        const int lane = tid & 63, wv = tid >> 6;
#pragma unroll
        for (int i = 0; i < 8; ++i) {
            float v = ss[i];
#pragma unroll
            for (int off = 32; off > 0; off >>= 1) v += __shfl_down(v, off, 64);
            if (lane == 0) red[wv * 8 + i] = v;
        }
        __syncthreads();
        if (tid < 8) {
            float tot = red[tid] + red[8 + tid] + red[16 + tid] + red[24 + tid];
            scale[m0 + tid] = mag[m0 + tid] / sqrtf(tot);
        }
    } else {
        const size_t base = (size_t)(blockIdx.x - 512) * 1024 + tid;
#pragma unroll
        for (int j = 0; j < 4; ++j) {
            const size_t idx = base + j * 256;
            float4 a = x4[idx];
            us4 o;
            o[0] = bf_rne(a.x); o[1] = bf_rne(a.y);
            o[2] = bf_rne(a.z); o[3] = bf_rne(a.w);
            xbf4[idx] = o;
        }
    }
}

// ---------------- GEMM: C[8192][4096] = xbf @ wbf^T * scale ----------------
// r7 persistent shell (256 blocks = 1/CU, 2 M-tiles/block, XCD N-ownership,
// 2 barriers/K-tile, B(t+2) self-buffer staging, vmcnt(4) counted tail) with a
// SKEWED operand pipeline: ds_reads for phase p+1 are issued BEFORE phase p's
// MFMA cluster behind a counted LGKM(4) that retains exactly those 4 reads.
// Per-wave ds_read->MFMA distance >= 1 cluster (~310 cyc) -> LDS latency hidden
// without relying on cross-wave TLP (only 2 waves/SIMD here).
// Staging/vmcnt invariants identical to r7 (proven):
//   tile t top:  A(t+1) -> buf[other] (4 gld_lds)
//   after BAR_mid: B(t+2) -> buf[cur].B (B reads retired pre-ph0-MFMA + barrier)
//   tile end: VMC(4) retires {B(t+1), A(t+1)}, keeps B(t+2); t>=62: VMC(0).
__global__ __launch_bounds__(512, 2) void dora_gemm(
    const unsigned short* __restrict__ xbf,   // [8192][4096] bf16
    const unsigned short* __restrict__ wbf,   // [4096][4096] bf16
    const float* __restrict__ scale,          // [4096]
    float* __restrict__ out) {                // [8192][4096] fp32
    constexpr int TSZ = 256 * 64;             // shorts per K-tile buffer (32 KiB)
    __shared__ __align__(16) unsigned short As[2 * TSZ];
    __shared__ __align__(16) unsigned short Bs[2 * TSZ];

    const int tid  = threadIdx.x;
    const int lane = tid & 63;
    const int w    = tid >> 6;     // wave 0..7
    const int wm   = w >> 2;       // 0..1  (M half: 128 rows)
    const int wn   = w & 3;        // 0..3  (N quarter: 64 cols)
    const int q    = lane >> 4;
    const int c15  = lane & 15;

    // persistent mapping: xcd = i&7, j = i>>3; N-panel = 2*xcd + (j&1); M-pair = j>>1
    const int xcd = blockIdx.x & 7;
    const int j   = blockIdx.x >> 3;          // 0..31
    const int tileN = (2 * xcd + (j & 1)) * 256;
    const int mp    = j >> 1;                 // 0..15

    // XOR swizzle: physical 16B chunk p of row r holds logical chunk p ^ (r&7)
    const int i8 = lane >> 3;
    const int lc = (lane & 7) ^ i8;     // pre-swizzled global source chunk

    const unsigned short* gB = wbf + (size_t)tileN * 4096;

    auto stage = [&](const unsigned short* __restrict__ g,
                     unsigned short* lbase, int T, int h) {
#pragma unroll
        for (int jj = 0; jj < 2; ++jj) {
            const int r0 = h * 128 + w * 16 + jj * 8;   // wave-uniform
            GLD_LDS16(g + (size_t)(r0 + i8) * 4096 + T * 64 + lc * 8,
                      lbase + r0 * 64);
        }
    };

    auto readA4 = [&](s16x8 (&af)[2][2], const unsigned short* Ac, int ph) {
#pragma unroll
        for (int i = 0; i < 2; ++i) {
            const int row = wm * 128 + (ph * 2 + i) * 16 + c15;
#pragma unroll
            for (int kc = 0; kc < 2; ++kc)
                af[i][kc] = *(const s16x8*)
                    &Ac[row * 64 + ((kc * 4 + q) ^ (row & 7)) * 8];
        }
    };

    for (int rep = 0; rep < 2; ++rep) {
        const int tileM = (mp * 2 + rep) * 256;
        const unsigned short* gA = xbf + (size_t)tileM * 4096;

        // pipeline prologue: tile0 (A+B) -> buf0, tile1 B -> buf1
        stage(gA, As, 0, 0); stage(gA, As, 0, 1);
        stage(gB, Bs, 0, 0); stage(gB, Bs, 0, 1);
        stage(gB, Bs + TSZ, 1, 0); stage(gB, Bs + TSZ, 1, 1);
        VMC(4);                         // tile0 landed; t1.B in flight
        __builtin_amdgcn_s_barrier();

        f32x4 acc[8][4] = {};

        auto mmac = [&](int ph, s16x8 (&af)[2][2], s16x8 (&b)[4][2]) {
            __builtin_amdgcn_s_setprio(1);
#pragma unroll
            for (int i = 0; i < 2; ++i)
#pragma unroll
                for (int nt = 0; nt < 4; ++nt)
#pragma unroll
                    for (int kc = 0; kc < 2; ++kc)
                        acc[ph * 2 + i][nt] = __builtin_amdgcn_mfma_f32_16x16x32_bf16(
                            af[i][kc], b[nt][kc], acc[ph * 2 + i][nt], 0, 0, 0);
            __builtin_amdgcn_s_setprio(0);
        };

#pragma unroll 2
        for (int t = 0; t < 64; ++t) {
            const int cur = t & 1;
            const unsigned short* Ac = As + cur * TSZ;
            unsigned short* Bc = Bs + cur * TSZ;
            unsigned short* An = As + (cur ^ 1) * TSZ;

            // ---- tile top: A(t+1) staging + B-frags + ph0/ph1 A-reads ----
            if (t < 63) { stage(gA, An, t + 1, 0); stage(gA, An, t + 1, 1); }

            s16x8 bfrag[4][2];
#pragma unroll
            for (int nt = 0; nt < 4; ++nt) {
                const int row = wn * 64 + nt * 16 + c15;
#pragma unroll
                for (int kc = 0; kc < 2; ++kc)
                    bfrag[nt][kc] = *(const s16x8*)
                        &Bc[row * 64 + ((kc * 4 + q) ^ (row & 7)) * 8];
            }
            s16x8 aP[2][2], aQ[2][2];
            readA4(aP, Ac, 0);
            SFENCE();                        // pin: {B, aP} issued before aQ
            readA4(aQ, Ac, 1);
            LGKM(4); SFENCE();               // B+aP retired; aQ (last 4) in flight

            mmac(0, aP, bfrag);              // ph0
            readA4(aP, Ac, 2);               // ph2 reads in flight
            LGKM(4); SFENCE();               // aQ retired; new aP in flight
            __builtin_amdgcn_s_barrier();    // BAR_mid (all waves' B reads done)
            SFENCE();

            if (t < 62) stage(gB, Bc, t + 2, 0);
            mmac(1, aQ, bfrag);              // ph1
            readA4(aQ, Ac, 3);               // ph3 reads in flight
            LGKM(4); SFENCE();               // aP(ph2) retired; aQ(ph3) in flight
            if (t < 62) stage(gB, Bc, t + 2, 1);
            mmac(2, aP, bfrag);              // ph2
            LGKM(0); SFENCE();               // aQ(ph3) retired
            mmac(3, aQ, bfrag);              // ph3

            if (t < 62) { VMC(4); }          // retires B(t+1)+A(t+1); B(t+2) flies
            else        { VMC(0); }
            __builtin_amdgcn_s_barrier();    // BAR_end
        }

        // epilogue: C/D layout col=lane&15, row=(lane>>4)*4+reg
#pragma unroll
        for (int nt = 0; nt < 4; ++nt) {
            const int col = tileN + wn * 64 + nt * 16 + c15;
            const float s = scale[col];
#pragma unroll
            for (int mt = 0; mt < 8; ++mt) {
                const int row0 = tileM + wm * 128 + mt * 16 + q * 4;
#pragma unroll
                for (int r = 0; r < 4; ++r)
                    out[(size_t)(row0 + r) * 4096 + col] = acc[mt][nt][r] * s;
            }
        }
        // BAR_end(t=63) drained vmcnt(0)+lgkmcnt(0) for all waves -> next rep safe
    }
}

extern "C" void kernel_launch(void* const* d_in, const int* in_sizes, int n_in,
                              void* d_out, int out_size, void* d_ws, size_t ws_size,
                              hipStream_t stream) {
    const float* x   = (const float*)d_in[0];   // [4,2048,4096]
    const float* W   = (const float*)d_in[1];   // [4096,4096]
    const float* A   = (const float*)d_in[2];   // [16,4096]
    const float* B   = (const float*)d_in[3];   // [4096,16]
    const float* mag = (const float*)d_in[4];   // [4096]
    float* out = (float*)d_out;

    const size_t XBF_BYTES = (size_t)8192 * 4096 * 2;  // 67,108,864
    const size_t WBF_BYTES = (size_t)4096 * 4096 * 2;  // 33,554,432
    const size_t NEEDED = XBF_BYTES + WBF_BYTES + 4096 * sizeof(float);
    if (ws_size < NEEDED) return;

    unsigned short* xbf = (unsigned short*)d_ws;
    unsigned short* wbf = (unsigned short*)((char*)d_ws + XBF_BYTES);
    float* scale = (float*)((char*)d_ws + XBF_BYTES + WBF_BYTES);

    prologue_kernel<<<8704, 256, 0, stream>>>((const float4*)x, (us4*)xbf,
                                              (const float4*)W, (const float4*)A,
                                              B, mag, wbf, scale);
    dora_gemm<<<256, 512, 0, stream>>>(xbf, wbf, scale, out);
}

// Round 9
// 504.928 us; speedup vs baseline: 1.1121x; 1.1121x over previous
//
#include <hip/hip_runtime.h>
#include <stdint.h>

typedef __attribute__((ext_vector_type(8))) short s16x8;    // bf16 MFMA A/B frag (4 VGPRs)
typedef __attribute__((ext_vector_type(4))) float f32x4;    // MFMA C/D frag
typedef __attribute__((ext_vector_type(4))) unsigned short us4;

// ---- bf16 round-to-nearest-even (inputs are finite normals) ----
__device__ inline unsigned short bf_rne(float f) {
    union { float f; uint32_t u; } v; v.f = f;
    uint32_t u = v.u;
    u += 0x7FFFu + ((u >> 16) & 1u);
    return (unsigned short)(u >> 16);
}

// async global->LDS, 16B per lane; LDS dst is wave-uniform base + lane*16
#define GLD_LDS16(gp, lp)                                                     \
    __builtin_amdgcn_global_load_lds(                                         \
        (const __attribute__((address_space(1))) void*)(gp),                  \
        (__attribute__((address_space(3))) void*)(lp), 16, 0, 0)

#define LGKM(n) asm volatile("s_waitcnt lgkmcnt(" #n ")" ::: "memory")
#define VMC(n)  asm volatile("s_waitcnt vmcnt(" #n ")" ::: "memory")
#define SFENCE() __builtin_amdgcn_sched_barrier(0)

// ---------------- Fused prologue ----------------
// blocks [0,1024):     prep — adapted = W + B@A -> bf16, scale = mag/rownorm, 4 rows/blk
// blocks [1024,9216):  cvt  — x fp32 -> bf16, unit-stride float4 -> us4 (proven form)
__global__ __launch_bounds__(256) void prologue_kernel(
    const float4* __restrict__ x4, us4* __restrict__ xbf4,
    const float4* __restrict__ W4,
    const float4* __restrict__ A4,   // [16][1024] float4
    const float* __restrict__ B,     // [4096][16]
    const float* __restrict__ mag,   // [4096]
    unsigned short* __restrict__ wbf,
    float* __restrict__ scale) {
    const int tid = threadIdx.x;
    if (blockIdx.x < 1024) {
        const int m0 = blockIdx.x * 4;
        __shared__ float4 Bsh4[4][4];    // 4 rows x 16 floats
        __shared__ float red[16];
        if (tid < 64) ((float*)Bsh4)[tid] = B[m0 * 16 + tid];
        __syncthreads();
        float ss[4] = {};
        for (int c = tid; c < 1024; c += 256) {   // 4 iters
            float4 w[4];
#pragma unroll
            for (int i = 0; i < 4; ++i) w[i] = W4[(size_t)(m0 + i) * 1024 + c];
#pragma unroll
            for (int rg = 0; rg < 4; ++rg) {
                float4 a[4];
#pragma unroll
                for (int r = 0; r < 4; ++r) a[r] = A4[(rg * 4 + r) * 1024 + c];
#pragma unroll
                for (int i = 0; i < 4; ++i) {
                    const float4 b = Bsh4[i][rg];
                    w[i].x += b.x * a[0].x + b.y * a[1].x + b.z * a[2].x + b.w * a[3].x;
                    w[i].y += b.x * a[0].y + b.y * a[1].y + b.z * a[2].y + b.w * a[3].y;
                    w[i].z += b.x * a[0].z + b.y * a[1].z + b.z * a[2].z + b.w * a[3].z;
                    w[i].w += b.x * a[0].w + b.y * a[1].w + b.z * a[2].w + b.w * a[3].w;
                }
            }
#pragma unroll
            for (int i = 0; i < 4; ++i) {
                ss[i] += w[i].x * w[i].x + w[i].y * w[i].y + w[i].z * w[i].z + w[i].w * w[i].w;
                us4 o; o[0] = bf_rne(w[i].x); o[1] = bf_rne(w[i].y);
                o[2] = bf_rne(w[i].z); o[3] = bf_rne(w[i].w);
                *(us4*)&wbf[(size_t)(m0 + i) * 4096 + c * 4] = o;
            }
        }
        const int lane = tid & 63, wv = tid >> 6;
#pragma unroll
        for (int i = 0; i < 4; ++i) {
            float v = ss[i];
#pragma unroll
            for (int off = 32; off > 0; off >>= 1) v += __shfl_down(v, off, 64);
            if (lane == 0) red[wv * 4 + i] = v;
        }
        __syncthreads();
        if (tid < 4) {
            float tot = red[tid] + red[4 + tid] + red[8 + tid] + red[12 + tid];
            scale[m0 + tid] = mag[m0 + tid] / sqrtf(tot);
        }
    } else {
        const size_t base = (size_t)(blockIdx.x - 1024) * 1024 + tid;
#pragma unroll
        for (int j = 0; j < 4; ++j) {
            const size_t idx = base + j * 256;
            float4 a = x4[idx];
            us4 o;
            o[0] = bf_rne(a.x); o[1] = bf_rne(a.y);
            o[2] = bf_rne(a.z); o[3] = bf_rne(a.w);
            xbf4[idx] = o;
        }
    }
}

// ---------------- GEMM: C[8192][4096] = xbf @ wbf^T * scale ----------------
// SESSION CHAMPION (r7: 264.5us GEMM, 519.2us total, MfmaUtil 45.7%, 0 conflicts).
// r3-proven K-loop wrapped in a persistent 2-tile block: 256 blocks (1/CU),
// each block computes TWO M-adjacent tiles of the SAME N-panel. XCD ownership:
// block i -> xcd=i&7 owns N-panels {2*xcd, 2*xcd+1}; per-XCD B working set =
// 4MB ~= private L2. x panels shared across XCDs via L3.
// K-loop (per tile): 2 barriers/K-tile.
//   BAR_mid after quadrant-0 MFMA (all B-frag ds_reads retired) -> overwrite
//   buf[cur].B with B(t+2). BAR_end after counted vmcnt(4) (A(t+1) landed,
//   B(t+2) stays in flight). Tail t>=62: vmcnt(0).
// NOTE (r8 post-mortem): skewed counted-lgkm operand pipeline REGRESSED
// (276.7us, MfmaUtil 44.2) — do not re-add. Five schedule variants all land
// 264-280us; the 45% plateau is robust to source-level reordering here.
__global__ __launch_bounds__(512, 2) void dora_gemm(
    const unsigned short* __restrict__ xbf,   // [8192][4096] bf16
    const unsigned short* __restrict__ wbf,   // [4096][4096] bf16
    const float* __restrict__ scale,          // [4096]
    float* __restrict__ out) {                // [8192][4096] fp32
    constexpr int TSZ = 256 * 64;             // shorts per K-tile buffer (32 KiB)
    __shared__ __align__(16) unsigned short As[2 * TSZ];
    __shared__ __align__(16) unsigned short Bs[2 * TSZ];

    const int tid  = threadIdx.x;
    const int lane = tid & 63;
    const int w    = tid >> 6;     // wave 0..7
    const int wm   = w >> 2;       // 0..1  (M half: 128 rows)
    const int wn   = w & 3;        // 0..3  (N quarter: 64 cols)
    const int q    = lane >> 4;
    const int c15  = lane & 15;

    // persistent mapping: xcd = i&7, j = i>>3; N-panel = 2*xcd + (j&1);
    // M-pair = j>>1 -> tiles (2*mp, n), (2*mp+1, n)
    const int xcd = blockIdx.x & 7;
    const int j   = blockIdx.x >> 3;          // 0..31
    const int tileN = (2 * xcd + (j & 1)) * 256;
    const int mp    = j >> 1;                 // 0..15

    // A staging: XOR swizzle, physical 16B chunk p of row r holds logical p ^ (r&7)
    const int i8 = lane >> 3;
    const int lc = (lane & 7) ^ i8;     // pre-swizzled global source chunk

    const unsigned short* gB = wbf + (size_t)tileN * 4096;
    const float sc = scale[tileN + wn * 64 + 0 * 16 + c15];  // kept simple below

    auto stage = [&](const unsigned short* __restrict__ g,
                     unsigned short* lbase, int T, int h) {
#pragma unroll
        for (int jj = 0; jj < 2; ++jj) {
            const int r0 = h * 128 + w * 16 + jj * 8;   // wave-uniform
            GLD_LDS16(g + (size_t)(r0 + i8) * 4096 + T * 64 + lc * 8,
                      lbase + r0 * 64);
        }
    };

    for (int rep = 0; rep < 2; ++rep) {
        const int tileM = (mp * 2 + rep) * 256;
        const unsigned short* gA = xbf + (size_t)tileM * 4096;

        // pipeline prologue: tile0 (A+B) -> buf0, tile1 B -> buf1
        stage(gA, As, 0, 0); stage(gA, As, 0, 1);
        stage(gB, Bs, 0, 0); stage(gB, Bs, 0, 1);
        stage(gB, Bs + TSZ, 1, 0); stage(gB, Bs + TSZ, 1, 1);
        VMC(4);                         // tile0 landed; t1.B in flight
        __builtin_amdgcn_s_barrier();

        f32x4 acc[8][4] = {};

#pragma unroll 2
        for (int t = 0; t < 64; ++t) {
            const int cur = t & 1;
            const unsigned short* Ac = As + cur * TSZ;
            unsigned short* Bc = Bs + cur * TSZ;
            unsigned short* An = As + (cur ^ 1) * TSZ;

            // earliest-possible A(t+1) stage (dest last read during t-1)
            if (t < 63) { stage(gA, An, t + 1, 0); stage(gA, An, t + 1, 1); }

            // B-frags for the whole tile (8 x ds_read_b128), held in regs
            s16x8 bfrag[4][2];
#pragma unroll
            for (int nt = 0; nt < 4; ++nt) {
                const int row = wn * 64 + nt * 16 + c15;
#pragma unroll
                for (int kc = 0; kc < 2; ++kc)
                    bfrag[nt][kc] = *(const s16x8*)
                        &Bc[row * 64 + ((kc * 4 + q) ^ (row & 7)) * 8];
            }

            // quadrant 0 (mt 0,1): consumes ALL bfrag -> retires B reads
            {
                s16x8 af[2][2];
#pragma unroll
                for (int i = 0; i < 2; ++i) {
                    const int row = wm * 128 + i * 16 + c15;
#pragma unroll
                    for (int kc = 0; kc < 2; ++kc)
                        af[i][kc] = *(const s16x8*)
                            &Ac[row * 64 + ((kc * 4 + q) ^ (row & 7)) * 8];
                }
                __builtin_amdgcn_s_setprio(1);
#pragma unroll
                for (int i = 0; i < 2; ++i)
#pragma unroll
                    for (int nt = 0; nt < 4; ++nt)
#pragma unroll
                        for (int kc = 0; kc < 2; ++kc)
                            acc[i][nt] = __builtin_amdgcn_mfma_f32_16x16x32_bf16(
                                af[i][kc], bfrag[nt][kc], acc[i][nt], 0, 0, 0);
                __builtin_amdgcn_s_setprio(0);
            }

            LGKM(0); SFENCE();
            __builtin_amdgcn_s_barrier();                 // BAR_mid

            if (t < 62) stage(gB, Bc, t + 2, 0);

            // quadrants 1..3 (mt 2..7), barrier-free
#pragma unroll
            for (int ph = 1; ph < 4; ++ph) {
                if (ph == 2 && t < 62) stage(gB, Bc, t + 2, 1);
                s16x8 af[2][2];
#pragma unroll
                for (int i = 0; i < 2; ++i) {
                    const int row = wm * 128 + (ph * 2 + i) * 16 + c15;
#pragma unroll
                    for (int kc = 0; kc < 2; ++kc)
                        af[i][kc] = *(const s16x8*)
                            &Ac[row * 64 + ((kc * 4 + q) ^ (row & 7)) * 8];
                }
                __builtin_amdgcn_s_setprio(1);
#pragma unroll
                for (int i = 0; i < 2; ++i)
#pragma unroll
                    for (int nt = 0; nt < 4; ++nt)
#pragma unroll
                        for (int kc = 0; kc < 2; ++kc)
                            acc[ph * 2 + i][nt] = __builtin_amdgcn_mfma_f32_16x16x32_bf16(
                                af[i][kc], bfrag[nt][kc], acc[ph * 2 + i][nt], 0, 0, 0);
                __builtin_amdgcn_s_setprio(0);
            }

            if (t < 62) { VMC(4); }
            else        { VMC(0); }
            __builtin_amdgcn_s_barrier();                 // BAR_end
        }

        // epilogue: C/D layout col=lane&15, row=(lane>>4)*4+reg
#pragma unroll
        for (int nt = 0; nt < 4; ++nt) {
            const int col = tileN + wn * 64 + nt * 16 + c15;
            const float s = scale[col];
#pragma unroll
            for (int mt = 0; mt < 8; ++mt) {
                const int row0 = tileM + wm * 128 + mt * 16 + q * 4;
#pragma unroll
                for (int r = 0; r < 4; ++r)
                    out[(size_t)(row0 + r) * 4096 + col] = acc[mt][nt][r] * s;
            }
        }
        // epilogue has no LDS access; next rep's first stage is safe after
        // BAR_end(t=63) drained vmcnt(0)+lgkmcnt(0) for all waves.
    }
    (void)sc;
}

extern "C" void kernel_launch(void* const* d_in, const int* in_sizes, int n_in,
                              void* d_out, int out_size, void* d_ws, size_t ws_size,
                              hipStream_t stream) {
    const float* x   = (const float*)d_in[0];   // [4,2048,4096]
    const float* W   = (const float*)d_in[1];   // [4096,4096]
    const float* A   = (const float*)d_in[2];   // [16,4096]
    const float* B   = (const float*)d_in[3];   // [4096,16]
    const float* mag = (const float*)d_in[4];   // [4096]
    float* out = (float*)d_out;

    const size_t XBF_BYTES = (size_t)8192 * 4096 * 2;  // 67,108,864
    const size_t WBF_BYTES = (size_t)4096 * 4096 * 2;  // 33,554,432
    const size_t NEEDED = XBF_BYTES + WBF_BYTES + 4096 * sizeof(float);
    if (ws_size < NEEDED) return;

    unsigned short* xbf = (unsigned short*)d_ws;
    unsigned short* wbf = (unsigned short*)((char*)d_ws + XBF_BYTES);
    float* scale = (float*)((char*)d_ws + XBF_BYTES + WBF_BYTES);

    prologue_kernel<<<9216, 256, 0, stream>>>((const float4*)x, (us4*)xbf,
                                              (const float4*)W, (const float4*)A,
                                              B, mag, wbf, scale);
    dora_gemm<<<256, 512, 0, stream>>>(xbf, wbf, scale, out);
}